// Round 5
// baseline (135.799 us; speedup 1.0000x reference)
//
#include <hip/hip_runtime.h>
#include <math.h>

#define N_NODES 1024
#define N_EVAL 131072
#define NUM_POLES 8
#define PI_D 3.14159265358979323846

typedef float v2f __attribute__((ext_vector_type(2)));

// ============================================================================
// V6: node-pair merge + packed FP32 (VOP3P) evaluation.
//
// Evidence V1-V5: wall time tracks total VALU instruction count (V2 4 ops/
// node-pt -> 60us; V5 5.5 -> 75.8us) while structure/occupancy/delivery-path
// changes do nothing; every wave ~90% stalled, stalls correlated per SIMD
// (effective fixed issue rate ~21-29% VALUBusy). Lever: cut instructions.
//
//  1. Pair merge (setup-time): wv0/(x-a)+wv1/(x-b) =
//     (wv0*d1 + wv1*d0) * rcp(d0*d1), d0=x-a, d1=x-b. Halves rcp count.
//     d's computed directly (Sterbenz-exact near nodes -> no cancellation).
//  2. Packed fp32: each thread evaluates 2 points as float2; v_pk_* VOP3P
//     ops take 64-bit sources, so every pair constant is stored DUPLICATED
//     {c,c} -> loads into an SGPR pair used directly as a packed source
//     (one scalar operand per instruction). 9 pk-VALU + 2 rcp per pair per
//     2 points vs V2's 16 + 4.
//
// Layout in d_ws (floats): [0,1024) nodes, [1024,2048) w, [2048,3072) w*v
// (kept for the rare exact-hit fixup), then 512 pairs x 6 duplicated float2:
// {-a,-a},{-b,-b},{wv0,wv0},{wv1,wv1},{w0,w0},{w1,w1}  (24KB; total 36KB).
//
// Weights: for Chebyshev pts of the 2nd kind, 1/prod_{i!=j}(x_j-x_i) =
// (-1)^j*delta_j*2^(n-1)/n; uniform positive scalings cancel in num/den, so
// w_j = (-1)^j * delta_j * prod_m((x_j-pr_m)^2 + pi_m^2).
// Exact node hits: q=0 -> inf/NaN poisons the point -> NaN fixup rescans the
// original per-node arrays (reference: exact-hit column reduces to
// sum(hit w*v)/sum(hit w)).
// ============================================================================

__global__ __launch_bounds__(256) void setup_kernel(
    const float* __restrict__ values,
    const float* __restrict__ poles_real,
    const float* __restrict__ poles_imag,
    float* __restrict__ ws) {
    const int j = blockIdx.x * 256 + threadIdx.x;
    const double nd = cos(PI_D * (double)j / (double)(N_NODES - 1));
    double prod = (j == 0 || j == N_NODES - 1) ? 0.5 : 1.0;
#pragma unroll
    for (int m = 0; m < NUM_POLES; ++m) {
        const double dr = nd - (double)poles_real[m];
        const double di = (double)poles_imag[m];
        prod *= dr * dr + di * di;
    }
    if (j & 1) prod = -prod;
    ws[j]        = (float)nd;
    ws[j + 1024] = (float)prod;
    ws[j + 2048] = (float)(prod * (double)values[j]);
}

__global__ __launch_bounds__(256) void setup_pairs_kernel(float* __restrict__ ws) {
    const int k = blockIdx.x * 256 + threadIdx.x;   // pair index 0..511
    const float a   = ws[2 * k];
    const float b   = ws[2 * k + 1];
    const float w0  = ws[1024 + 2 * k];
    const float w1  = ws[1024 + 2 * k + 1];
    const float wv0 = ws[2048 + 2 * k];
    const float wv1 = ws[2048 + 2 * k + 1];
    float2* p = (float2*)(ws + 3072) + k * 6;
    p[0] = make_float2(-a, -a);
    p[1] = make_float2(-b, -b);
    p[2] = make_float2(wv0, wv0);
    p[3] = make_float2(wv1, wv1);
    p[4] = make_float2(w0, w0);
    p[5] = make_float2(w1, w1);
}

__global__ __launch_bounds__(256) void eval_pk_kernel(
    const float* __restrict__ x_eval,
    const float* __restrict__ ws,
    float* __restrict__ out) {
    __shared__ float2 s_rA[4][64];   // per-wave partial for points [0,64)
    __shared__ float2 s_rB[4][64];   // per-wave partial for points [64,128)

    const int t = threadIdx.x;
    const int lane = t & 63;
    // Wave-uniform so the constant-stream addresses scalarize (s_load).
    const int wid = __builtin_amdgcn_readfirstlane(t >> 6);   // 0..3
    const int pbase = blockIdx.x * 128;

    v2f X;
    X.x = x_eval[pbase + lane];
    X.y = x_eval[pbase + 64 + lane];

    // This wave's 128 pairs (256 nodes): 6 duplicated-float2 constants each.
    const v2f* __restrict__ pc = (const v2f*)(ws + 3072) + wid * (128 * 6);

    v2f A0 = {0.0f, 0.0f}, B0 = {0.0f, 0.0f};
    v2f A1 = {0.0f, 0.0f}, B1 = {0.0f, 0.0f};

#define PAIR(KK, AA, BB)                                                     \
    {                                                                        \
        const v2f* c = pc + (KK) * 6;                                        \
        const v2f D0 = X + c[0];                /* x - a (pk_add) */         \
        const v2f D1 = X + c[1];                /* x - b */                  \
        const v2f Q  = D0 * D1;                 /* pk_mul */                 \
        v2f R;                                                               \
        R.x = __builtin_amdgcn_rcpf(Q.x);                                    \
        R.y = __builtin_amdgcn_rcpf(Q.y);                                    \
        const v2f Nv = __builtin_elementwise_fma(c[2], D1, c[3] * D0);       \
        const v2f Nw = __builtin_elementwise_fma(c[4], D1, c[5] * D0);       \
        AA = __builtin_elementwise_fma(Nv, R, AA);                           \
        BB = __builtin_elementwise_fma(Nw, R, BB);                           \
    }

    // 128 pairs, alternating accumulator sets for ILP; zero VMEM in loop
    // (constants via wave-uniform s_load stream).
#pragma unroll 4
    for (int k = 0; k < 128; k += 2) {
        PAIR(k, A0, B0)
        PAIR(k + 1, A1, B1)
    }
#undef PAIR

    const v2f A = A0 + A1;
    const v2f B = B0 + B1;
    s_rA[wid][lane] = make_float2(A.x, B.x);
    s_rB[wid][lane] = make_float2(A.y, B.y);
    __syncthreads();

    if (t < 128) {
        const int half = t >> 6;          // 0: points [0,64), 1: [64,128)
        const int idx  = t & 63;
        float num = 0.0f, den = 0.0f;
#pragma unroll
        for (int w = 0; w < 4; ++w) {
            const float2 p = half ? s_rB[w][idx] : s_rA[w][idx];
            num += p.x;
            den += p.y;
        }
        float res = num / den;
        if (__builtin_expect(__builtin_isnan(res), 0)) {
            const float xv = x_eval[pbase + t];
            float hn = 0.0f, hd = 0.0f;
            for (int jj = 0; jj < N_NODES; ++jj) {
                if (ws[jj] == xv) { hn += ws[2048 + jj]; hd += ws[1024 + jj]; }
            }
            res = hn / hd;
        }
        out[pbase + t] = res;
    }
}

// ============================================================================
// Fallback (verified round-0 kernel) if the harness workspace is too small.
// ============================================================================
__global__ __launch_bounds__(512, 4) void eval_kernel_fused(
    const float* __restrict__ x_eval,
    const float* __restrict__ values,
    const float* __restrict__ poles_real,
    const float* __restrict__ poles_imag,
    float* __restrict__ out) {
    __shared__ __align__(16) float s_n[N_NODES];
    __shared__ __align__(16) float s_w[N_NODES];
    __shared__ __align__(16) float s_v[N_NODES];
    __shared__ float2 s_r[8][256];

    const int t = threadIdx.x;

#pragma unroll
    for (int h = 0; h < 2; ++h) {
        const int j = t + h * 512;
        const double nd = cos(PI_D * (double)j / (double)(N_NODES - 1));
        double prod = (j == 0 || j == N_NODES - 1) ? 0.5 : 1.0;
#pragma unroll
        for (int m = 0; m < NUM_POLES; ++m) {
            const double dr = nd - (double)poles_real[m];
            const double di = (double)poles_imag[m];
            prod *= dr * dr + di * di;
        }
        if (j & 1) prod = -prod;
        s_n[j] = (float)nd;
        s_w[j] = (float)prod;
        s_v[j] = (float)(prod * (double)values[j]);
    }
    __syncthreads();

    const int lane = t & 63;
    const int wid  = t >> 6;
    const int pbase = blockIdx.x * 256;
    const float x0 = x_eval[pbase + lane];
    const float x1 = x_eval[pbase + 64 + lane];
    const float x2 = x_eval[pbase + 128 + lane];
    const float x3 = x_eval[pbase + 192 + lane];

    const float4* n4 = (const float4*)s_n + wid * 32;
    const float4* w4 = (const float4*)s_w + wid * 32;
    const float4* v4 = (const float4*)s_v + wid * 32;

    float a0 = 0.0f, b0 = 0.0f, a1 = 0.0f, b1 = 0.0f;
    float a2 = 0.0f, b2 = 0.0f, a3 = 0.0f, b3 = 0.0f;

#define NODE(C)                                                            \
    {                                                                      \
        const float d0 = x0 - an.C;                                        \
        const float d1 = x1 - an.C;                                        \
        const float d2 = x2 - an.C;                                        \
        const float d3 = x3 - an.C;                                        \
        const float r0 = __builtin_amdgcn_rcpf(d0);                        \
        const float r1 = __builtin_amdgcn_rcpf(d1);                        \
        const float r2 = __builtin_amdgcn_rcpf(d2);                        \
        const float r3 = __builtin_amdgcn_rcpf(d3);                        \
        a0 = fmaf(av.C, r0, a0); b0 = fmaf(aw.C, r0, b0);                  \
        a1 = fmaf(av.C, r1, a1); b1 = fmaf(aw.C, r1, b1);                  \
        a2 = fmaf(av.C, r2, a2); b2 = fmaf(aw.C, r2, b2);                  \
        a3 = fmaf(av.C, r3, a3); b3 = fmaf(aw.C, r3, b3);                  \
    }

#pragma unroll 4
    for (int q = 0; q < 32; ++q) {
        const float4 an = n4[q];
        const float4 aw = w4[q];
        const float4 av = v4[q];
        NODE(x) NODE(y) NODE(z) NODE(w)
    }
#undef NODE

    s_r[wid][lane]       = make_float2(a0, b0);
    s_r[wid][lane + 64]  = make_float2(a1, b1);
    s_r[wid][lane + 128] = make_float2(a2, b2);
    s_r[wid][lane + 192] = make_float2(a3, b3);
    __syncthreads();

    if (t < 256) {
        float nn = 0.0f, dd = 0.0f;
#pragma unroll
        for (int w = 0; w < 8; ++w) {
            const float2 pr = s_r[w][t];
            nn += pr.x;
            dd += pr.y;
        }
        float res = nn / dd;
        if (__builtin_expect(__builtin_isnan(res), 0)) {
            const float x = x_eval[pbase + t];
            float hn = 0.0f, hd = 0.0f;
            for (int j = 0; j < N_NODES; ++j) {
                if (s_n[j] == x) { hn += s_v[j]; hd += s_w[j]; }
            }
            res = hn / hd;
        }
        out[pbase + t] = res;
    }
}

extern "C" void kernel_launch(void* const* d_in, const int* in_sizes, int n_in,
                              void* d_out, int out_size, void* d_ws, size_t ws_size,
                              hipStream_t stream) {
    const float* x_eval     = (const float*)d_in[0];
    const float* values     = (const float*)d_in[1];
    const float* poles_real = (const float*)d_in[2];
    const float* poles_imag = (const float*)d_in[3];
    float* out = (float*)d_out;

    if (ws_size >= (3072 + 512 * 12) * sizeof(float)) {
        float* ws = (float*)d_ws;
        setup_kernel<<<N_NODES / 256, 256, 0, stream>>>(values, poles_real,
                                                        poles_imag, ws);
        setup_pairs_kernel<<<2, 256, 0, stream>>>(ws);
        eval_pk_kernel<<<N_EVAL / 128, 256, 0, stream>>>(x_eval, ws, out);
    } else {
        eval_kernel_fused<<<N_EVAL / 256, 512, 0, stream>>>(
            x_eval, values, poles_real, poles_imag, out);
    }
}